// Round 1
// baseline (287.957 us; speedup 1.0000x reference)
//
#include <hip/hip_runtime.h>

// Problem constants (from reference setup_inputs)
#define Bq 2
#define Cq 2
#define Dq 128
#define Hq 224
#define Wq 224

// out[b,c,z,h,w] = src[b,c,z0,h,w]*(1-wz) + src[b,c,z1,h,w]*wz
// where zc = clamp(z + flow[b,0,z,h,w], 0, D-1), z0=floor(zc), wz=zc-z0,
// z1=min(z0+1,D-1).  y/x displacement is zero -> pure z-linear interp.
__global__ __launch_bounds__(256) void st_zwarp_kernel(
    const float* __restrict__ src, const float* __restrict__ flow,
    float* __restrict__ out)
{
    const int HW  = Hq * Wq;        // 50176
    const int DHW = Dq * HW;        // 6422528
    const int N4  = (Bq * DHW) / 4; // 3,211,264 quads

    int i4 = blockIdx.x * blockDim.x + threadIdx.x;
    if (i4 >= N4) return;
    int e = i4 * 4;                 // flat index into [B,D,H,W]
    int b = e / DHW;
    int r = e - b * DHW;            // z*HW + h*W + w
    int z = r / HW;
    int hw = r - z * HW;            // h*W + w  (w multiple of 4)

    // flow is [B,1,D,H,W] -> flat index b*DHW + r
    float4 f = *(const float4*)(flow + b * DHW + r);
    float fl[4] = {f.x, f.y, f.z, f.w};

    int z0[4], z1[4];
    float wz[4];
#pragma unroll
    for (int j = 0; j < 4; ++j) {
        float zc = (float)z + fl[j];
        zc = fminf(fmaxf(zc, 0.0f), (float)(Dq - 1));
        float zf = floorf(zc);
        z0[j] = (int)zf;
        wz[j] = zc - zf;
        z1[j] = min(z0[j] + 1, Dq - 1);
    }

    const float* src_b = src + b * (Cq * DHW) + hw;   // + c*DHW + z*HW + j
    float*       out_b = out + b * (Cq * DHW) + r;    // + c*DHW

#pragma unroll
    for (int c = 0; c < Cq; ++c) {
        const float* sc = src_b + c * DHW;
        float4 o;
        float* op = (float*)&o;
#pragma unroll
        for (int j = 0; j < 4; ++j) {
            float s0 = sc[z0[j] * HW + j];
            float s1 = sc[z1[j] * HW + j];
            op[j] = s0 * (1.0f - wz[j]) + s1 * wz[j];
        }
        *(float4*)(out_b + c * DHW) = o;
    }
}

extern "C" void kernel_launch(void* const* d_in, const int* in_sizes, int n_in,
                              void* d_out, int out_size, void* d_ws, size_t ws_size,
                              hipStream_t stream) {
    const float* src  = (const float*)d_in[0];
    const float* flow = (const float*)d_in[1];
    float* out = (float*)d_out;

    const int N4 = (Bq * Dq * Hq * Wq) / 4;   // 3,211,264
    const int block = 256;
    const int grid = (N4 + block - 1) / block; // 12,544
    st_zwarp_kernel<<<grid, block, 0, stream>>>(src, flow, out);
}

// Round 2
// 228.143 us; speedup vs baseline: 1.2622x; 1.2622x over previous
//
#include <hip/hip_runtime.h>

// Problem constants (from reference setup_inputs)
#define Bq 2
#define Cq 2
#define Dq 128
#define Hq 224
#define Wq 224
#define HWq (Hq * Wq)          // 50176
#define DHWq (Dq * HWq)        // 6422528
#define CDHWq (Cq * DHWq)      // 12845056
#define WT 32                  // w-tile width (224 = 7*32)
#define NWT (Wq / WT)          // 7

// out[b,c,z,h,w] = src[b,c,z0,h,w]*(1-wz) + src[b,c,z1,h,w]*wz
// zc = clamp(z + flow[b,0,z,h,w], 0, D-1), z0=floor(zc), wz=zc-z0,
// z1=min(z0+1, D-1).  Only z is displaced -> a block owning (b,h,w-tile)
// with ALL z needs exactly src[b,:,:,h,w-tile]: no halo, each src element
// is fetched from HBM exactly once globally.
__global__ __launch_bounds__(256) void st_zwarp_lds_kernel(
    const float* __restrict__ src, const float* __restrict__ flow,
    float* __restrict__ out)
{
    __shared__ float s[Cq * Dq * WT];   // 32 KB: s[c][z][w]

    const int tid = threadIdx.x;
    int blk = blockIdx.x;
    const int wt = blk % NWT;
    blk /= NWT;
    const int h = blk % Hq;
    const int b = blk / Hq;

    // ---- stage src[b, :, :, h, wt*32 .. +32) into LDS (float4, coalesced)
    const float* src_b = src + b * CDHWq + h * Wq + wt * WT;
    for (int i4 = tid; i4 < (Cq * Dq * WT) / 4; i4 += 256) {
        const int i = i4 * 4;               // flat LDS float index
        const int c = i >> 12;              // / (128*32)
        const int z = (i >> 5) & (Dq - 1);  // /32 % 128
        const int w = i & (WT - 1);
        *(float4*)(&s[i]) = *(const float4*)(src_b + c * DHWq + z * HWq + w);
    }
    __syncthreads();

    // ---- compute: thread = (zg, w); each thread does 16 z values
    const int w  = tid & (WT - 1);
    const int zg = tid >> 5;                // 0..7
    const float* flow_b = flow + b * DHWq + h * Wq + wt * WT + w;
    float*       out_b  = out  + b * CDHWq + h * Wq + wt * WT + w;

#pragma unroll
    for (int k = 0; k < Dq / 8; ++k) {
        const int z = zg * (Dq / 8) + k;
        const float fl = flow_b[z * HWq];
        float zc = fminf(fmaxf((float)z + fl, 0.0f), (float)(Dq - 1));
        const float zf = floorf(zc);
        const int z0 = (int)zf;
        const float wz = zc - zf;
        const int z1 = min(z0 + 1, Dq - 1);
#pragma unroll
        for (int c = 0; c < Cq; ++c) {
            const float s0 = s[c * (Dq * WT) + z0 * WT + w];
            const float s1 = s[c * (Dq * WT) + z1 * WT + w];
            out_b[c * DHWq + z * HWq] = s0 + (s1 - s0) * wz;
        }
    }
}

extern "C" void kernel_launch(void* const* d_in, const int* in_sizes, int n_in,
                              void* d_out, int out_size, void* d_ws, size_t ws_size,
                              hipStream_t stream) {
    const float* src  = (const float*)d_in[0];
    const float* flow = (const float*)d_in[1];
    float* out = (float*)d_out;

    const int grid = Bq * Hq * NWT;   // 3136
    st_zwarp_lds_kernel<<<grid, 256, 0, stream>>>(src, flow, out);
}